// Round 1
// baseline (2311.532 us; speedup 1.0000x reference)
//
#include <hip/hip_runtime.h>
#include <math.h>

#define EPS 1e-8f

// ---------------------------------------------------------------------------
// Pass 1: per-edge outer products scattered into per-node S, plus sum of w.
// ---------------------------------------------------------------------------
__global__ __launch_bounds__(256) void edge_pass1(
    const float* __restrict__ mu0, const float* __restrict__ mu,
    const int* __restrict__ ei, const int* __restrict__ ej,
    float* __restrict__ S, double* __restrict__ sums, int E)
{
    int tid = blockIdx.x * blockDim.x + threadIdx.x;
    double wv = 0.0;
    if (tid < E) {
        int i = ei[tid];
        int j = ej[tid];
        float a0 = mu0[3*i+0], a1 = mu0[3*i+1], a2 = mu0[3*i+2];
        float b0 = mu0[3*j+0], b1 = mu0[3*j+1], b2 = mu0[3*j+2];
        float r0 = b0 - a0, r1 = b1 - a1, r2 = b2 - a2;
        float c0 = mu[3*i+0], c1 = mu[3*i+1], c2 = mu[3*i+2];
        float e0 = mu[3*j+0], e1 = mu[3*j+1], e2 = mu[3*j+2];
        float d0 = e0 - c0, d1 = e1 - c1, d2 = e2 - c2;
        float w = 1.0f / (sqrtf(r0*r0 + r1*r1 + r2*r2) + EPS);
        wv = (double)w;
        float* Si = S + (size_t)9 * i;
        float wd0 = w * d0, wd1 = w * d1, wd2 = w * d2;
        atomicAdd(Si + 0, wd0 * r0);
        atomicAdd(Si + 1, wd0 * r1);
        atomicAdd(Si + 2, wd0 * r2);
        atomicAdd(Si + 3, wd1 * r0);
        atomicAdd(Si + 4, wd1 * r1);
        atomicAdd(Si + 5, wd1 * r2);
        atomicAdd(Si + 6, wd2 * r0);
        atomicAdd(Si + 7, wd2 * r1);
        atomicAdd(Si + 8, wd2 * r2);
    }
    // wave-64 reduction of w into double accumulator
    #pragma unroll
    for (int off = 32; off > 0; off >>= 1)
        wv += __shfl_down(wv, off);
    if ((threadIdx.x & 63) == 0)
        atomicAdd(sums + 0, wv);
}

// ---------------------------------------------------------------------------
// Pass 2: per-node nearest rotation via scaled Newton polar iteration.
// Replicates the reference det-fix: if det(UVh) < 0, negate FIRST COLUMN.
// ---------------------------------------------------------------------------
__global__ __launch_bounds__(256) void node_pass(
    const float* __restrict__ S, float* __restrict__ R, int N)
{
    int n = blockIdx.x * blockDim.x + threadIdx.x;
    if (n >= N) return;
    float X[9];
    #pragma unroll
    for (int k = 0; k < 9; ++k) X[k] = S[(size_t)9 * n + k];

    bool ok = true;
    #pragma unroll
    for (int it = 0; it < 8; ++it) {
        // cofactor matrix C: X^{-T} = C / det
        float c00 =  (X[4]*X[8] - X[5]*X[7]);
        float c01 = -(X[3]*X[8] - X[5]*X[6]);
        float c02 =  (X[3]*X[7] - X[4]*X[6]);
        float c10 = -(X[1]*X[8] - X[2]*X[7]);
        float c11 =  (X[0]*X[8] - X[2]*X[6]);
        float c12 = -(X[0]*X[7] - X[1]*X[6]);
        float c20 =  (X[1]*X[5] - X[2]*X[4]);
        float c21 = -(X[0]*X[5] - X[2]*X[3]);
        float c22 =  (X[0]*X[4] - X[1]*X[3]);
        float det = X[0]*c00 + X[1]*c01 + X[2]*c02;
        if (!(fabsf(det) > 1e-30f)) { ok = false; break; }
        float inv_det = 1.0f / det;
        float Y[9] = { c00*inv_det, c01*inv_det, c02*inv_det,
                       c10*inv_det, c11*inv_det, c12*inv_det,
                       c20*inv_det, c21*inv_det, c22*inv_det };
        float nx = 0.f, ny = 0.f;
        #pragma unroll
        for (int k = 0; k < 9; ++k) { nx += X[k]*X[k]; ny += Y[k]*Y[k]; }
        float g = sqrtf(sqrtf(ny / nx));     // gamma = (||Y||/||X||)^(1/2)
        float hg = 0.5f * g, hig = 0.5f / g;
        #pragma unroll
        for (int k = 0; k < 9; ++k) X[k] = hg * X[k] + hig * Y[k];
    }
    if (!ok) {
        // degenerate S: fall back to identity
        X[0] = 1.f; X[1] = 0.f; X[2] = 0.f;
        X[3] = 0.f; X[4] = 1.f; X[5] = 0.f;
        X[6] = 0.f; X[7] = 0.f; X[8] = 1.f;
    }
    // det fix (reference quirk): det<0 -> negate first column of R
    float det = X[0]*(X[4]*X[8] - X[5]*X[7])
              - X[1]*(X[3]*X[8] - X[5]*X[6])
              + X[2]*(X[3]*X[7] - X[4]*X[6]);
    if (det < 0.f) { X[0] = -X[0]; X[3] = -X[3]; X[6] = -X[6]; }
    #pragma unroll
    for (int k = 0; k < 9; ++k) R[(size_t)9 * n + k] = X[k];
}

// ---------------------------------------------------------------------------
// Pass 3: per-edge residual, accumulate sum(w * ||deform - R_i rest||^2).
// ---------------------------------------------------------------------------
__global__ __launch_bounds__(256) void edge_pass2(
    const float* __restrict__ mu0, const float* __restrict__ mu,
    const int* __restrict__ ei, const int* __restrict__ ej,
    const float* __restrict__ R, double* __restrict__ sums, int E)
{
    int tid = blockIdx.x * blockDim.x + threadIdx.x;
    double cv = 0.0;
    if (tid < E) {
        int i = ei[tid];
        int j = ej[tid];
        float a0 = mu0[3*i+0], a1 = mu0[3*i+1], a2 = mu0[3*i+2];
        float b0 = mu0[3*j+0], b1 = mu0[3*j+1], b2 = mu0[3*j+2];
        float r0 = b0 - a0, r1 = b1 - a1, r2 = b2 - a2;
        float c0 = mu[3*i+0], c1 = mu[3*i+1], c2 = mu[3*i+2];
        float e0 = mu[3*j+0], e1 = mu[3*j+1], e2 = mu[3*j+2];
        float d0 = e0 - c0, d1 = e1 - c1, d2 = e2 - c2;
        float w = 1.0f / (sqrtf(r0*r0 + r1*r1 + r2*r2) + EPS);
        const float* Ri = R + (size_t)9 * i;
        float p0 = Ri[0]*r0 + Ri[1]*r1 + Ri[2]*r2;
        float p1 = Ri[3]*r0 + Ri[4]*r1 + Ri[5]*r2;
        float p2 = Ri[6]*r0 + Ri[7]*r1 + Ri[8]*r2;
        float x0 = d0 - p0, x1 = d1 - p1, x2 = d2 - p2;
        cv = (double)(w * (x0*x0 + x1*x1 + x2*x2));
    }
    #pragma unroll
    for (int off = 32; off > 0; off >>= 1)
        cv += __shfl_down(cv, off);
    if ((threadIdx.x & 63) == 0)
        atomicAdd(sums + 1, cv);
}

__global__ void finalize(const double* __restrict__ sums, float* __restrict__ out)
{
    out[0] = (float)(0.01 * (sums[1] / sums[0]));
}

extern "C" void kernel_launch(void* const* d_in, const int* in_sizes, int n_in,
                              void* d_out, int out_size, void* d_ws, size_t ws_size,
                              hipStream_t stream) {
    const float* mu0 = (const float*)d_in[0];
    const float* mu  = (const float*)d_in[1];
    const int*   eidx = (const int*)d_in[2];
    int N = in_sizes[0] / 3;
    int E = in_sizes[2] / 2;
    const int* ei = eidx;
    const int* ej = eidx + E;

    // workspace layout: [0,16): double sums[2]; [16,...): S (N*9 f32); then R
    double* sums = (double*)d_ws;
    float*  S    = (float*)((char*)d_ws + 16);
    float*  R    = S + (size_t)N * 9;

    // zero sums + S (workspace is poisoned with 0xAA before every call)
    hipMemsetAsync(d_ws, 0, 16 + (size_t)N * 9 * sizeof(float), stream);

    int eb = (E + 255) / 256;
    int nb = (N + 255) / 256;
    edge_pass1<<<eb, 256, 0, stream>>>(mu0, mu, ei, ej, S, sums, E);
    node_pass <<<nb, 256, 0, stream>>>(S, R, N);
    edge_pass2<<<eb, 256, 0, stream>>>(mu0, mu, ei, ej, R, sums, E);
    finalize  <<<1, 1, 0, stream>>>(sums, (float*)d_out);
}